// Round 1
// baseline (3088.575 us; speedup 1.0000x reference)
//
#include <hip/hip_runtime.h>
#include <hip/hip_bf16.h>
#include <math.h>

namespace {

constexpr int Bc  = 32;
constexpr int Tc  = 1024;
constexpr int Dc  = 1024;
constexpr int Nt  = 77;
constexpr int Lc  = 768;
constexpr int HDc = 128;
constexpr int TEDc = 2048;
constexpr float EPSc = 1e-5f;

__device__ __forceinline__ float silu_f(float x) {
  return x / (1.f + __expf(-x));
}

// ---------------- per-row mean/rstd (for LayerNorm fused into GEMM A-staging) ------------
__global__ void row_stats_kernel(const float* __restrict__ A, float* __restrict__ stats, int cols) {
  const int row = blockIdx.x;
  const float* p = A + (size_t)row * cols;
  float s = 0.f, sq = 0.f;
  for (int c = threadIdx.x * 4; c < cols; c += blockDim.x * 4) {
    float4 v = *reinterpret_cast<const float4*>(p + c);
    s  += v.x + v.y + v.z + v.w;
    sq += v.x * v.x + v.y * v.y + v.z * v.z + v.w * v.w;
  }
  __shared__ float red[2][4];
  for (int o = 32; o > 0; o >>= 1) { s += __shfl_down(s, o); sq += __shfl_down(sq, o); }
  const int wid = threadIdx.x >> 6, lane = threadIdx.x & 63;
  if (lane == 0) { red[0][wid] = s; red[1][wid] = sq; }
  __syncthreads();
  if (threadIdx.x == 0) {
    float S = red[0][0] + red[0][1] + red[0][2] + red[0][3];
    float SQ = red[1][0] + red[1][1] + red[1][2] + red[1][3];
    float mean = S / cols;
    float var = SQ / cols - mean * mean;
    stats[row * 2 + 0] = mean;
    stats[row * 2 + 1] = rsqrtf(var + EPSc);
  }
}

// ---------------- generic tiled fp32 GEMM: C = pro(A) @ W + bias (+x) -------------------
// PRO: 0 = none, 1 = LayerNorm rows (stats,gvec,bvec), 2 = SiLU
// EPI: 0 = none, 1 = add residual xres
template<int PRO, int EPI>
__global__ __launch_bounds__(256) void gemm_f32(
    const float* __restrict__ A, const float* __restrict__ W,
    const float* __restrict__ bias, float* __restrict__ C,
    int M, int K, int Nn,
    const float* __restrict__ stats, const float* __restrict__ gvec,
    const float* __restrict__ bvec, const float* __restrict__ xres)
{
  __shared__ float As[16][132];   // A tile transposed: As[k][m]
  __shared__ float Ws[16][132];   // W tile: Ws[k][n]
  const int tid = threadIdx.x;
  const int bn0 = blockIdx.x * 128;
  const int bm0 = blockIdx.y * 128;
  const int tx = tid & 15, ty = tid >> 4;
  float acc[8][8] = {};
  for (int k0 = 0; k0 < K; k0 += 16) {
    #pragma unroll
    for (int vv = 0; vv < 2; vv++) {
      const int v = tid + vv * 256;
      // A: 128 rows x 4 float4
      {
        const int r = v >> 2, c4 = (v & 3) * 4;
        const int gr = bm0 + r, gc = k0 + c4;
        float4 val = make_float4(0.f, 0.f, 0.f, 0.f);
        if (gr < M) {
          val = *reinterpret_cast<const float4*>(A + (size_t)gr * K + gc);
          if (PRO == 1) {
            const float mean = stats[gr * 2], rstd = stats[gr * 2 + 1];
            val.x = (val.x - mean) * rstd * gvec[gc + 0] + bvec[gc + 0];
            val.y = (val.y - mean) * rstd * gvec[gc + 1] + bvec[gc + 1];
            val.z = (val.z - mean) * rstd * gvec[gc + 2] + bvec[gc + 2];
            val.w = (val.w - mean) * rstd * gvec[gc + 3] + bvec[gc + 3];
          } else if (PRO == 2) {
            val.x = silu_f(val.x); val.y = silu_f(val.y);
            val.z = silu_f(val.z); val.w = silu_f(val.w);
          }
        }
        As[c4 + 0][r] = val.x;
        As[c4 + 1][r] = val.y;
        As[c4 + 2][r] = val.z;
        As[c4 + 3][r] = val.w;
      }
      // W: 16 rows x 32 float4
      {
        const int wr = v >> 5, wc4 = (v & 31) * 4;
        float4 wv = *reinterpret_cast<const float4*>(W + (size_t)(k0 + wr) * Nn + bn0 + wc4);
        *reinterpret_cast<float4*>(&Ws[wr][wc4]) = wv;
      }
    }
    __syncthreads();
    #pragma unroll
    for (int kk = 0; kk < 16; kk++) {
      float a[8], w[8];
      #pragma unroll
      for (int i = 0; i < 8; i++) a[i] = As[kk][ty + 16 * i];
      #pragma unroll
      for (int j = 0; j < 8; j++) w[j] = Ws[kk][tx + 16 * j];
      #pragma unroll
      for (int i = 0; i < 8; i++)
        #pragma unroll
        for (int j = 0; j < 8; j++)
          acc[i][j] += a[i] * w[j];
    }
    __syncthreads();
  }
  #pragma unroll
  for (int i = 0; i < 8; i++) {
    const int gr = bm0 + ty + 16 * i;
    if (gr >= M) continue;
    #pragma unroll
    for (int j = 0; j < 8; j++) {
      const int gc = bn0 + tx + 16 * j;
      float val = acc[i][j] + bias[gc];
      if (EPI == 1) val += xres[(size_t)gr * Nn + gc];
      C[(size_t)gr * Nn + gc] = val;
    }
  }
}

// ---------------- softmax over head_dim (128 contiguous) : one wave per segment ---------
__global__ void softmax_q_kernel(float* __restrict__ q) {
  const int seg = blockIdx.x * 4 + (threadIdx.x >> 6);   // (b*T+t)*H + h
  const int lane = threadIdx.x & 63;
  float* p = q + (size_t)seg * HDc;
  float v0 = p[lane], v1 = p[lane + 64];
  float m = fmaxf(v0, v1);
  for (int o = 32; o > 0; o >>= 1) m = fmaxf(m, __shfl_xor(m, o));
  float e0 = __expf(v0 - m), e1 = __expf(v1 - m);
  float s = e0 + e1;
  for (int o = 32; o > 0; o >>= 1) s += __shfl_xor(s, o);
  const float inv = 1.f / s;
  p[lane] = e0 * inv;
  p[lane + 64] = e1 * inv;
}

// ---------------- softmax over N (=77) for each (b, d) column ---------------------------
__global__ void softmax_k_kernel(float* __restrict__ k) {
  const int idx = blockIdx.x * blockDim.x + threadIdx.x;  // b*D + d
  const int b = idx >> 10, d = idx & 1023;
  float* p = k + (size_t)b * Nt * Dc + d;
  float m = -1e30f;
  for (int n = 0; n < Nt; n++) m = fmaxf(m, p[(size_t)n * Dc]);
  float s = 0.f;
  for (int n = 0; n < Nt; n++) s += __expf(p[(size_t)n * Dc] - m);
  const float inv = 1.f / s;
  for (int n = 0; n < Nt; n++) p[(size_t)n * Dc] = __expf(p[(size_t)n * Dc] - m) * inv;
}

// ---------------- attn[b,h,dd,dl] = sum_n k[b,n,h,dd] * v[b,n,h,dl] ---------------------
__global__ __launch_bounds__(256) void attn_einsum_kernel(
    const float* __restrict__ k, const float* __restrict__ v, float* __restrict__ attn) {
  const int bh = blockIdx.x;
  const int b = bh >> 3, h = bh & 7;
  __shared__ float ks[Nt][HDc];
  __shared__ float vs[Nt][HDc];
  const float* kb = k + (size_t)b * Nt * Dc + h * HDc;
  const float* vb = v + (size_t)b * Nt * Dc + h * HDc;
  for (int i = threadIdx.x; i < Nt * HDc; i += 256) {
    const int n = i >> 7, d = i & 127;
    ks[n][d] = kb[(size_t)n * Dc + d];
    vs[n][d] = vb[(size_t)n * Dc + d];
  }
  __syncthreads();
  const int tx = threadIdx.x & 15, ty = threadIdx.x >> 4;
  float acc[8][8] = {};
  for (int n = 0; n < Nt; n++) {
    float a[8], w[8];
    #pragma unroll
    for (int i = 0; i < 8; i++) a[i] = ks[n][ty + 16 * i];
    #pragma unroll
    for (int j = 0; j < 8; j++) w[j] = vs[n][tx + 16 * j];
    #pragma unroll
    for (int i = 0; i < 8; i++)
      #pragma unroll
      for (int j = 0; j < 8; j++)
        acc[i][j] += a[i] * w[j];
  }
  float* ab = attn + (size_t)bh * HDc * HDc;
  #pragma unroll
  for (int i = 0; i < 8; i++)
    #pragma unroll
    for (int j = 0; j < 8; j++)
      ab[(size_t)(ty + 16 * i) * HDc + tx + 16 * j] = acc[i][j];
}

// ---------------- y = q @ attn per (b,h), in place over q -------------------------------
__global__ __launch_bounds__(256) void y_inplace_kernel(
    float* __restrict__ q, const float* __restrict__ attn) {
  const int bh = blockIdx.y;
  const int b = bh >> 3, h = bh & 7;
  const int row0 = blockIdx.x * 64;
  __shared__ float at[HDc][HDc];       // 64 KB
  __shared__ float qt[64][HDc + 1];    // 33 KB (padded: column reads conflict-free)
  const float* ap = attn + (size_t)bh * HDc * HDc;
  for (int i = threadIdx.x; i < HDc * HDc; i += 256)
    at[i >> 7][i & 127] = ap[i];
  float* qbase = q + ((size_t)(b * Tc + row0)) * Dc + h * HDc;
  for (int i = threadIdx.x; i < 64 * 32; i += 256) {
    const int r = i >> 5, c4 = (i & 31) * 4;
    float4 v = *reinterpret_cast<const float4*>(qbase + (size_t)r * Dc + c4);
    qt[r][c4 + 0] = v.x; qt[r][c4 + 1] = v.y; qt[r][c4 + 2] = v.z; qt[r][c4 + 3] = v.w;
  }
  __syncthreads();
  const int tx = threadIdx.x & 15, ty = threadIdx.x >> 4;
  float acc[4][8] = {};
  for (int kk = 0; kk < HDc; kk++) {
    float a[4], w[8];
    #pragma unroll
    for (int i = 0; i < 4; i++) a[i] = qt[ty + 16 * i][kk];
    #pragma unroll
    for (int j = 0; j < 8; j++) w[j] = at[kk][tx + 16 * j];
    #pragma unroll
    for (int i = 0; i < 4; i++)
      #pragma unroll
      for (int j = 0; j < 8; j++)
        acc[i][j] += a[i] * w[j];
  }
  #pragma unroll
  for (int i = 0; i < 4; i++)
    #pragma unroll
    for (int j = 0; j < 8; j++)
      qbase[(size_t)(ty + 16 * i) * Dc + tx + 16 * j] = acc[i][j];
}

// ---------------- LN(y)*(1+scale)+shift -> SiLU, in place -------------------------------
__global__ __launch_bounds__(256) void ln_mod_silu_kernel(
    float* __restrict__ y, const float* __restrict__ ss,
    const float* __restrict__ g, const float* __restrict__ bvec) {
  const int row = blockIdx.x;          // b*T + t
  const int b = row >> 10;
  float* p = y + (size_t)row * Dc;
  const int c = threadIdx.x * 4;
  float4 v4 = *reinterpret_cast<const float4*>(p + c);
  float vv[4] = {v4.x, v4.y, v4.z, v4.w};
  float s = vv[0] + vv[1] + vv[2] + vv[3];
  float sq = vv[0]*vv[0] + vv[1]*vv[1] + vv[2]*vv[2] + vv[3]*vv[3];
  __shared__ float red[2][4];
  __shared__ float mr[2];
  for (int o = 32; o > 0; o >>= 1) { s += __shfl_down(s, o); sq += __shfl_down(sq, o); }
  const int wid = threadIdx.x >> 6, lane = threadIdx.x & 63;
  if (lane == 0) { red[0][wid] = s; red[1][wid] = sq; }
  __syncthreads();
  if (threadIdx.x == 0) {
    const float S  = red[0][0] + red[0][1] + red[0][2] + red[0][3];
    const float SQ = red[1][0] + red[1][1] + red[1][2] + red[1][3];
    const float mean = S / Dc;
    const float var = SQ / Dc - mean * mean;
    mr[0] = mean; mr[1] = rsqrtf(var + EPSc);
  }
  __syncthreads();
  const float mean = mr[0], rstd = mr[1];
  const float* ssb = ss + (size_t)b * 2 * Dc;
  float o[4];
  #pragma unroll
  for (int u = 0; u < 4; u++) {
    float val = (vv[u] - mean) * rstd * g[c + u] + bvec[c + u];
    val = val * (1.f + ssb[c + u]) + ssb[Dc + c + u];
    o[u] = silu_f(val);
  }
  *reinterpret_cast<float4*>(p + c) = make_float4(o[0], o[1], o[2], o[3]);
}

}  // namespace

extern "C" void kernel_launch(void* const* d_in, const int* in_sizes, int n_in,
                              void* d_out, int out_size, void* d_ws, size_t ws_size,
                              hipStream_t stream) {
  const float* x       = (const float*)d_in[0];
  const float* xf      = (const float*)d_in[1];
  const float* emb     = (const float*)d_in[2];
  const float* norm_g  = (const float*)d_in[3];
  const float* norm_b  = (const float*)d_in[4];
  const float* tnorm_g = (const float*)d_in[5];
  const float* tnorm_b = (const float*)d_in[6];
  const float* Wq      = (const float*)d_in[7];
  const float* bq      = (const float*)d_in[8];
  const float* Wk      = (const float*)d_in[9];
  const float* bk      = (const float*)d_in[10];
  const float* Wv      = (const float*)d_in[11];
  const float* bv_     = (const float*)d_in[12];
  const float* emb_W   = (const float*)d_in[13];
  const float* emb_b   = (const float*)d_in[14];
  const float* onorm_g = (const float*)d_in[15];
  const float* onorm_b = (const float*)d_in[16];
  const float* Wo      = (const float*)d_in[17];
  const float* bo      = (const float*)d_in[18];
  float* out = (float*)d_out;

  float* ws = (float*)d_ws;
  size_t off = 0;
  float* stat_x  = ws + off; off += (size_t)Bc * Tc * 2;        // 65536
  float* stat_xf = ws + off; off += 8192;                        // 2464*2 padded
  float* qs      = ws + off; off += (size_t)Bc * Tc * Dc;        // 33.55M (q -> y -> act)
  float* kbuf    = ws + off; off += (size_t)Bc * Nt * Dc;        // 2.52M
  float* vbuf    = ws + off; off += (size_t)Bc * Nt * Dc;        // 2.52M
  float* attnb   = ws + off; off += (size_t)Bc * 8 * HDc * HDc;  // 4.19M
  float* ssb     = ws + off; off += (size_t)Bc * 2 * Dc;         // 65536

  const int Mq = Bc * Tc;        // 32768
  const int Mkv = Bc * Nt;       // 2464

  // 1) row stats for both LayerNorms that feed GEMMs
  row_stats_kernel<<<Mq, 256, 0, stream>>>(x, stat_x, Dc);
  row_stats_kernel<<<Mkv, 256, 0, stream>>>(xf, stat_xf, Lc);

  // 2) q = LN(x) @ Wq + bq
  gemm_f32<1, 0><<<dim3(Dc / 128, Mq / 128), 256, 0, stream>>>(
      x, Wq, bq, qs, Mq, Dc, Dc, stat_x, norm_g, norm_b, nullptr);
  // 3) softmax over head_dim
  softmax_q_kernel<<<(Mq * 8) / 4, 256, 0, stream>>>(qs);

  // 4) k,v = LN(xf) @ Wk/Wv + b
  gemm_f32<1, 0><<<dim3(Dc / 128, (Mkv + 127) / 128), 256, 0, stream>>>(
      xf, Wk, bk, kbuf, Mkv, Lc, Dc, stat_xf, tnorm_g, tnorm_b, nullptr);
  gemm_f32<1, 0><<<dim3(Dc / 128, (Mkv + 127) / 128), 256, 0, stream>>>(
      xf, Wv, bv_, vbuf, Mkv, Lc, Dc, stat_xf, tnorm_g, tnorm_b, nullptr);
  // 5) softmax over N
  softmax_k_kernel<<<(Bc * Dc) / 256, 256, 0, stream>>>(kbuf);
  // 6) attn = sum_n k (x) v
  attn_einsum_kernel<<<Bc * 8, 256, 0, stream>>>(kbuf, vbuf, attnb);

  // 7) scale/shift = silu(emb) @ emb_W + emb_b
  gemm_f32<2, 0><<<dim3((2 * Dc) / 128, 1), 256, 0, stream>>>(
      emb, emb_W, emb_b, ssb, Bc, TEDc, 2 * Dc, nullptr, nullptr, nullptr, nullptr);

  // 8) y = q @ attn (in place), then LN*(1+scale)+shift -> SiLU (in place)
  y_inplace_kernel<<<dim3(Tc / 64, Bc * 8), 256, 0, stream>>>(qs, attnb);
  ln_mod_silu_kernel<<<Mq, 256, 0, stream>>>(qs, ssb, onorm_g, onorm_b);

  // 9) out = x + act @ Wo + bo
  gemm_f32<0, 1><<<dim3(Dc / 128, Mq / 128), 256, 0, stream>>>(
      qs, Wo, bo, out, Mq, Dc, Dc, nullptr, nullptr, nullptr, x);
}

// Round 2
// 1143.777 us; speedup vs baseline: 2.7003x; 2.7003x over previous
//
#include <hip/hip_runtime.h>
#include <hip/hip_bf16.h>
#include <math.h>

namespace {

constexpr int Bc  = 32;
constexpr int Tc  = 1024;
constexpr int Dc  = 1024;
constexpr int Nt  = 77;
constexpr int Lc  = 768;
constexpr int HDc = 128;
constexpr int TEDc = 2048;
constexpr float EPSc = 1e-5f;

typedef __attribute__((ext_vector_type(8))) short bf16x8;
typedef __attribute__((ext_vector_type(4))) float f32x4;

__device__ __forceinline__ float silu_f(float x) { return x / (1.f + __expf(-x)); }

__device__ __forceinline__ unsigned short f2bf(float f) {
  unsigned u = __float_as_uint(f);
  return (unsigned short)((u + 0x7fffu + ((u >> 16) & 1u)) >> 16);
}
__device__ __forceinline__ float bf2f(unsigned short h) {
  return __uint_as_float(((unsigned)h) << 16);
}

__device__ __forceinline__ void gload16(const void* g, void* l) {
  __builtin_amdgcn_global_load_lds((const __attribute__((address_space(1))) void*)g,
                                   (__attribute__((address_space(3))) void*)l, 16, 0, 0);
}

// ---------- fused LayerNorm -> bf16 matrix (one block per row) --------------------------
__global__ __launch_bounds__(256) void ln_bf16_kernel(
    const float* __restrict__ src, unsigned short* __restrict__ dst, int cols,
    const float* __restrict__ g, const float* __restrict__ b)
{
  const int row = blockIdx.x;
  const float* p = src + (size_t)row * cols;
  const int c = threadIdx.x * 4;
  float4 v = make_float4(0.f, 0.f, 0.f, 0.f);
  if (c < cols) v = *reinterpret_cast<const float4*>(p + c);
  float s  = v.x + v.y + v.z + v.w;
  float sq = v.x * v.x + v.y * v.y + v.z * v.z + v.w * v.w;
  __shared__ float red[2][4];
  __shared__ float mr[2];
  for (int o = 32; o > 0; o >>= 1) { s += __shfl_down(s, o); sq += __shfl_down(sq, o); }
  const int wid = threadIdx.x >> 6, lane = threadIdx.x & 63;
  if (lane == 0) { red[0][wid] = s; red[1][wid] = sq; }
  __syncthreads();
  if (threadIdx.x == 0) {
    const float S  = red[0][0] + red[0][1] + red[0][2] + red[0][3];
    const float SQ = red[1][0] + red[1][1] + red[1][2] + red[1][3];
    const float mean = S / cols;
    const float var  = SQ / cols - mean * mean;
    mr[0] = mean; mr[1] = rsqrtf(var + EPSc);
  }
  __syncthreads();
  if (c < cols) {
    const float mean = mr[0], rstd = mr[1];
    ushort4 o;
    o.x = f2bf((v.x - mean) * rstd * g[c + 0] + b[c + 0]);
    o.y = f2bf((v.y - mean) * rstd * g[c + 1] + b[c + 1]);
    o.z = f2bf((v.z - mean) * rstd * g[c + 2] + b[c + 2]);
    o.w = f2bf((v.w - mean) * rstd * g[c + 3] + b[c + 3]);
    *reinterpret_cast<ushort4*>(dst + (size_t)row * cols + c) = o;
  }
}

// ---------- transpose-convert W[K][N] f32 -> Wt[N][K] bf16 ------------------------------
__global__ __launch_bounds__(256) void convT_bf16_kernel(
    const float* __restrict__ W, unsigned short* __restrict__ Wt, int K, int N)
{
  __shared__ float t[32][33];
  const int n0 = blockIdx.x * 32, k0 = blockIdx.y * 32;
  const int tx = threadIdx.x & 31, ty = threadIdx.x >> 5;   // ty 0..7
  #pragma unroll
  for (int dy = 0; dy < 32; dy += 8)
    t[ty + dy][tx] = W[(size_t)(k0 + ty + dy) * N + n0 + tx];
  __syncthreads();
  #pragma unroll
  for (int dy = 0; dy < 32; dy += 8)
    Wt[(size_t)(n0 + ty + dy) * K + k0 + tx] = f2bf(t[tx][ty + dy]);
}

// ---------- bf16 MFMA GEMM: C[M][N] = A[M][K] @ Bt[N][K]^T + bias (+xres) ---------------
// m97 structure: 128x128 tile, 4 waves, BK=32, global_load_lds staging, 2 barriers/K-step
template<int OUTBF16, int ADDRES>
__global__ __launch_bounds__(256) void gemm_bf16_kernel(
    const unsigned short* __restrict__ A, const unsigned short* __restrict__ Bt,
    const float* __restrict__ bias, void* __restrict__ Cout,
    int M, int K, int N, const float* __restrict__ xres)
{
  __shared__ unsigned short As[128 * 32];
  __shared__ unsigned short Bs[128 * 32];
  const int tid = threadIdx.x, wid = tid >> 6, lane = tid & 63;
  const int ntx = N >> 7;
  const int bid = blockIdx.x, nwg = gridDim.x;
  int swz = bid;
  if ((nwg & 7) == 0) { const int cpx = nwg >> 3; swz = (bid & 7) * cpx + (bid >> 3); }
  const int bx = swz % ntx, by = swz / ntx;
  const int bm0 = by << 7, bn0 = bx << 7;
  const int wr = wid >> 1, wc = wid & 1, lhi = lane >> 4, llo = lane & 15;

  // staging assignment: wave `wid` owns LDS chunks (wid*2) and (wid*2+1), 1 KB each
  const int srow = lane >> 2;            // 0..15
  const int scol = (lane & 3) * 8;       // k element offset within tile
  int ar0 = bm0 + wid * 32 + srow;
  int ar1 = ar0 + 16;
  if (ar0 >= M) ar0 = M - 1;
  if (ar1 >= M) ar1 = M - 1;
  const int br0 = bn0 + wid * 32 + srow;     // N is multiple of 128: always valid
  const int br1 = br0 + 16;
  const unsigned short* Ag0 = A  + (size_t)ar0 * K + scol;
  const unsigned short* Ag1 = A  + (size_t)ar1 * K + scol;
  const unsigned short* Bg0 = Bt + (size_t)br0 * K + scol;
  const unsigned short* Bg1 = Bt + (size_t)br1 * K + scol;
  unsigned short* Al0 = &As[(wid * 2 + 0) * 512];
  unsigned short* Al1 = &As[(wid * 2 + 1) * 512];
  unsigned short* Bl0 = &Bs[(wid * 2 + 0) * 512];
  unsigned short* Bl1 = &Bs[(wid * 2 + 1) * 512];

  const unsigned short* afb = &As[(wr * 64 + llo) * 32 + lhi * 8];
  const unsigned short* bfb = &Bs[(wc * 64 + llo) * 32 + lhi * 8];

  f32x4 acc[4][4] = {};

  for (int k0 = 0; k0 < K; k0 += 32) {
    gload16(Ag0 + k0, Al0);
    gload16(Ag1 + k0, Al1);
    gload16(Bg0 + k0, Bl0);
    gload16(Bg1 + k0, Bl1);
    __syncthreads();               // drains vmcnt before reads
    bf16x8 a_[4], b_[4];
    #pragma unroll
    for (int mi = 0; mi < 4; mi++) a_[mi] = *(const bf16x8*)(afb + mi * 512);
    #pragma unroll
    for (int ni = 0; ni < 4; ni++) b_[ni] = *(const bf16x8*)(bfb + ni * 512);
    #pragma unroll
    for (int mi = 0; mi < 4; mi++)
      #pragma unroll
      for (int ni = 0; ni < 4; ni++)
        acc[mi][ni] = __builtin_amdgcn_mfma_f32_16x16x32_bf16(a_[mi], b_[ni], acc[mi][ni], 0, 0, 0);
    __syncthreads();               // before overwriting LDS
  }

  #pragma unroll
  for (int mi = 0; mi < 4; mi++) {
    #pragma unroll
    for (int ni = 0; ni < 4; ni++) {
      const int col = bn0 + wc * 64 + ni * 16 + llo;
      const float bs = bias[col];
      #pragma unroll
      for (int r = 0; r < 4; r++) {
        const int row = bm0 + wr * 64 + mi * 16 + lhi * 4 + r;
        if (row < M) {
          float v = acc[mi][ni][r] + bs;
          if (ADDRES) v += xres[(size_t)row * N + col];
          if (OUTBF16) ((unsigned short*)Cout)[(size_t)row * N + col] = f2bf(v);
          else         ((float*)Cout)[(size_t)row * N + col] = v;
        }
      }
    }
  }
}

// ---------- softmax over head_dim (128 bf16), one wave per segment ----------------------
__global__ void softmax_q_bf16_kernel(unsigned short* __restrict__ q) {
  const int seg = blockIdx.x * 4 + (threadIdx.x >> 6);
  const int lane = threadIdx.x & 63;
  unsigned short* p = q + (size_t)seg * HDc + lane * 2;
  ushort2 u = *reinterpret_cast<const ushort2*>(p);
  float v0 = bf2f(u.x), v1 = bf2f(u.y);
  float m = fmaxf(v0, v1);
  for (int o = 32; o > 0; o >>= 1) m = fmaxf(m, __shfl_xor(m, o));
  float e0 = __expf(v0 - m), e1 = __expf(v1 - m);
  float ssum = e0 + e1;
  for (int o = 32; o > 0; o >>= 1) ssum += __shfl_xor(ssum, o);
  const float inv = 1.f / ssum;
  ushort2 o2; o2.x = f2bf(e0 * inv); o2.y = f2bf(e1 * inv);
  *reinterpret_cast<ushort2*>(p) = o2;
}

// ---------- softmax over N (=77) for each (b, d) column (fp32) --------------------------
__global__ void softmax_k_kernel(float* __restrict__ k) {
  const int idx = blockIdx.x * blockDim.x + threadIdx.x;  // b*D + d
  const int b = idx >> 10, d = idx & 1023;
  float* p = k + (size_t)b * Nt * Dc + d;
  float m = -1e30f;
  for (int n = 0; n < Nt; n++) m = fmaxf(m, p[(size_t)n * Dc]);
  float s = 0.f;
  for (int n = 0; n < Nt; n++) s += __expf(p[(size_t)n * Dc] - m);
  const float inv = 1.f / s;
  for (int n = 0; n < Nt; n++) p[(size_t)n * Dc] = __expf(p[(size_t)n * Dc] - m) * inv;
}

// ---------- attn[b,h,dd,dl] = sum_n k[b,n,h,dd] * v[b,n,h,dl] ---------------------------
__global__ __launch_bounds__(256) void attn_einsum_kernel(
    const float* __restrict__ k, const float* __restrict__ v, float* __restrict__ attn) {
  const int bh = blockIdx.x;
  const int b = bh >> 3, h = bh & 7;
  __shared__ float ks[Nt][HDc];
  __shared__ float vs[Nt][HDc];
  const float* kb = k + (size_t)b * Nt * Dc + h * HDc;
  const float* vb = v + (size_t)b * Nt * Dc + h * HDc;
  for (int i = threadIdx.x; i < Nt * HDc; i += 256) {
    const int n = i >> 7, d = i & 127;
    ks[n][d] = kb[(size_t)n * Dc + d];
    vs[n][d] = vb[(size_t)n * Dc + d];
  }
  __syncthreads();
  const int tx = threadIdx.x & 15, ty = threadIdx.x >> 4;
  float acc[8][8] = {};
  for (int n = 0; n < Nt; n++) {
    float a[8], w[8];
    #pragma unroll
    for (int i = 0; i < 8; i++) a[i] = ks[n][ty + 16 * i];
    #pragma unroll
    for (int j = 0; j < 8; j++) w[j] = vs[n][tx + 16 * j];
    #pragma unroll
    for (int i = 0; i < 8; i++)
      #pragma unroll
      for (int j = 0; j < 8; j++)
        acc[i][j] += a[i] * w[j];
  }
  float* ab = attn + (size_t)bh * HDc * HDc;
  #pragma unroll
  for (int i = 0; i < 8; i++)
    #pragma unroll
    for (int j = 0; j < 8; j++)
      ab[(size_t)(ty + 16 * i) * HDc + tx + 16 * j] = acc[i][j];
}

// ---------- y = q @ attn per (b,h), in place over q (bf16) ------------------------------
__global__ __launch_bounds__(256) void y_bf16_kernel(
    unsigned short* __restrict__ q, const float* __restrict__ attn) {
  const int bh = blockIdx.y;
  const int b = bh >> 3, h = bh & 7;
  const int row0 = blockIdx.x * 64;
  __shared__ float at[HDc][HDc];
  __shared__ float qt[64][HDc + 1];
  const float* ap = attn + (size_t)bh * HDc * HDc;
  for (int i = threadIdx.x; i < HDc * HDc; i += 256)
    at[i >> 7][i & 127] = ap[i];
  unsigned short* qbase = q + ((size_t)(b * Tc + row0)) * Dc + h * HDc;
  for (int i = threadIdx.x; i < 64 * 32; i += 256) {
    const int r = i >> 5, c4 = (i & 31) * 4;
    ushort4 u = *reinterpret_cast<const ushort4*>(qbase + (size_t)r * Dc + c4);
    qt[r][c4 + 0] = bf2f(u.x); qt[r][c4 + 1] = bf2f(u.y);
    qt[r][c4 + 2] = bf2f(u.z); qt[r][c4 + 3] = bf2f(u.w);
  }
  __syncthreads();
  const int tx = threadIdx.x & 15, ty = threadIdx.x >> 4;
  float acc[4][8] = {};
  for (int kk = 0; kk < HDc; kk++) {
    float a[4], w[8];
    #pragma unroll
    for (int i = 0; i < 4; i++) a[i] = qt[ty + 16 * i][kk];
    #pragma unroll
    for (int j = 0; j < 8; j++) w[j] = at[kk][tx + 16 * j];
    #pragma unroll
    for (int i = 0; i < 4; i++)
      #pragma unroll
      for (int j = 0; j < 8; j++)
        acc[i][j] += a[i] * w[j];
  }
  #pragma unroll
  for (int i = 0; i < 4; i++)
    #pragma unroll
    for (int j = 0; j < 8; j++)
      qbase[(size_t)(ty + 16 * i) * Dc + tx + 16 * j] = f2bf(acc[i][j]);
}

// ---------- LN(y)*(1+scale)+shift -> SiLU, in place (bf16) ------------------------------
__global__ __launch_bounds__(256) void ln_mod_silu_bf16_kernel(
    unsigned short* __restrict__ y, const float* __restrict__ ss,
    const float* __restrict__ g, const float* __restrict__ bvec) {
  const int row = blockIdx.x;          // b*T + t
  const int b = row >> 10;
  unsigned short* p = y + (size_t)row * Dc;
  const int c = threadIdx.x * 4;
  ushort4 u = *reinterpret_cast<const ushort4*>(p + c);
  float vv[4] = {bf2f(u.x), bf2f(u.y), bf2f(u.z), bf2f(u.w)};
  float s  = vv[0] + vv[1] + vv[2] + vv[3];
  float sq = vv[0]*vv[0] + vv[1]*vv[1] + vv[2]*vv[2] + vv[3]*vv[3];
  __shared__ float red[2][4];
  __shared__ float mr[2];
  for (int o = 32; o > 0; o >>= 1) { s += __shfl_down(s, o); sq += __shfl_down(sq, o); }
  const int wid = threadIdx.x >> 6, lane = threadIdx.x & 63;
  if (lane == 0) { red[0][wid] = s; red[1][wid] = sq; }
  __syncthreads();
  if (threadIdx.x == 0) {
    const float S  = red[0][0] + red[0][1] + red[0][2] + red[0][3];
    const float SQ = red[1][0] + red[1][1] + red[1][2] + red[1][3];
    const float mean = S / Dc;
    const float var = SQ / Dc - mean * mean;
    mr[0] = mean; mr[1] = rsqrtf(var + EPSc);
  }
  __syncthreads();
  const float mean = mr[0], rstd = mr[1];
  const float* ssb = ss + (size_t)b * 2 * Dc;
  ushort4 o;
  float t0 = (vv[0] - mean) * rstd * g[c + 0] + bvec[c + 0];
  float t1 = (vv[1] - mean) * rstd * g[c + 1] + bvec[c + 1];
  float t2 = (vv[2] - mean) * rstd * g[c + 2] + bvec[c + 2];
  float t3 = (vv[3] - mean) * rstd * g[c + 3] + bvec[c + 3];
  o.x = f2bf(silu_f(t0 * (1.f + ssb[c + 0]) + ssb[Dc + c + 0]));
  o.y = f2bf(silu_f(t1 * (1.f + ssb[c + 1]) + ssb[Dc + c + 1]));
  o.z = f2bf(silu_f(t2 * (1.f + ssb[c + 2]) + ssb[Dc + c + 2]));
  o.w = f2bf(silu_f(t3 * (1.f + ssb[c + 3]) + ssb[Dc + c + 3]));
  *reinterpret_cast<ushort4*>(p + c) = o;
}

// ---------- fp32 GEMM kept for the tiny emb projection (M=32) ---------------------------
__global__ __launch_bounds__(256) void gemm_emb_kernel(
    const float* __restrict__ A, const float* __restrict__ W,
    const float* __restrict__ bias, float* __restrict__ C,
    int M, int K, int Nn)
{
  __shared__ float As[16][132];
  __shared__ float Ws[16][132];
  const int tid = threadIdx.x;
  const int bn0 = blockIdx.x * 128;
  const int tx = tid & 15, ty = tid >> 4;
  float acc[8][8] = {};
  for (int k0 = 0; k0 < K; k0 += 16) {
    #pragma unroll
    for (int vv = 0; vv < 2; vv++) {
      const int v = tid + vv * 256;
      {
        const int r = v >> 2, c4 = (v & 3) * 4;
        const int gr = r, gc = k0 + c4;
        float4 val = make_float4(0.f, 0.f, 0.f, 0.f);
        if (gr < M) {
          val = *reinterpret_cast<const float4*>(A + (size_t)gr * K + gc);
          val.x = silu_f(val.x); val.y = silu_f(val.y);
          val.z = silu_f(val.z); val.w = silu_f(val.w);
        }
        As[c4 + 0][r] = val.x; As[c4 + 1][r] = val.y;
        As[c4 + 2][r] = val.z; As[c4 + 3][r] = val.w;
      }
      {
        const int wr = v >> 5, wc4 = (v & 31) * 4;
        float4 wv = *reinterpret_cast<const float4*>(W + (size_t)(k0 + wr) * Nn + bn0 + wc4);
        *reinterpret_cast<float4*>(&Ws[wr][wc4]) = wv;
      }
    }
    __syncthreads();
    #pragma unroll
    for (int kk = 0; kk < 16; kk++) {
      float a[8], w[8];
      #pragma unroll
      for (int i = 0; i < 8; i++) a[i] = As[kk][ty + 16 * i];
      #pragma unroll
      for (int j = 0; j < 8; j++) w[j] = Ws[kk][tx + 16 * j];
      #pragma unroll
      for (int i = 0; i < 8; i++)
        #pragma unroll
        for (int j = 0; j < 8; j++)
          acc[i][j] += a[i] * w[j];
    }
    __syncthreads();
  }
  #pragma unroll
  for (int i = 0; i < 8; i++) {
    const int gr = ty + 16 * i;
    if (gr >= M) continue;
    #pragma unroll
    for (int j = 0; j < 8; j++) {
      const int gc = bn0 + tx + 16 * j;
      C[(size_t)gr * Nn + gc] = acc[i][j] + bias[gc];
    }
  }
}

}  // namespace

extern "C" void kernel_launch(void* const* d_in, const int* in_sizes, int n_in,
                              void* d_out, int out_size, void* d_ws, size_t ws_size,
                              hipStream_t stream) {
  const float* x       = (const float*)d_in[0];
  const float* xf      = (const float*)d_in[1];
  const float* emb     = (const float*)d_in[2];
  const float* norm_g  = (const float*)d_in[3];
  const float* norm_b  = (const float*)d_in[4];
  const float* tnorm_g = (const float*)d_in[5];
  const float* tnorm_b = (const float*)d_in[6];
  const float* Wq      = (const float*)d_in[7];
  const float* bq      = (const float*)d_in[8];
  const float* Wk      = (const float*)d_in[9];
  const float* bk      = (const float*)d_in[10];
  const float* Wv      = (const float*)d_in[11];
  const float* bv_     = (const float*)d_in[12];
  const float* emb_W   = (const float*)d_in[13];
  const float* emb_b   = (const float*)d_in[14];
  const float* onorm_g = (const float*)d_in[15];
  const float* onorm_b = (const float*)d_in[16];
  const float* Wo      = (const float*)d_in[17];
  const float* bo      = (const float*)d_in[18];
  float* out = (float*)d_out;

  char* ws = (char*)d_ws;
  // region R (67.1 MB): first LN(x) bf16, later reused by the kv/attn chain
  unsigned short* Ab = (unsigned short*)ws;                       // 32768*1024 bf16
  char* R = ws;
  unsigned short* qb   = (unsigned short*)(ws + 67108864);        // q/y/act bf16 (in-place chain)
  unsigned short* Wq_t = (unsigned short*)(ws + 134217728);       // [1024][1024]
  unsigned short* Wk_t = (unsigned short*)(ws + 136314880);       // [1024][768]
  unsigned short* Wv_t = (unsigned short*)(ws + 137887744);       // [1024][768]
  unsigned short* Wo_t = (unsigned short*)(ws + 139460608);       // [1024][1024]
  float*          ssb  = (float*)(ws + 141557760);                // [32][2048]
  // kv-phase aliases inside R (valid because stream-serial after q-GEMM):
  unsigned short* xfb   = (unsigned short*)(R);                   // [2464][768] bf16
  float*          kbuf  = (float*)(R + 3784704);                  // [2464][1024]
  float*          vbuf  = (float*)(R + 13877248);                 // [2464][1024]
  float*          attnb = (float*)(R + 23969792);                 // [256][128][128]

  const int Mq  = Bc * Tc;   // 32768
  const int Mkv = Bc * Nt;   // 2464

  // ---- q path (uses Ab) ----
  ln_bf16_kernel<<<Mq, 256, 0, stream>>>(x, Ab, Dc, norm_g, norm_b);
  convT_bf16_kernel<<<dim3(Dc / 32, Dc / 32), 256, 0, stream>>>(Wq, Wq_t, Dc, Dc);
  convT_bf16_kernel<<<dim3(Dc / 32, Lc / 32), 256, 0, stream>>>(Wk, Wk_t, Lc, Dc);
  convT_bf16_kernel<<<dim3(Dc / 32, Lc / 32), 256, 0, stream>>>(Wv, Wv_t, Lc, Dc);
  convT_bf16_kernel<<<dim3(Dc / 32, Dc / 32), 256, 0, stream>>>(Wo, Wo_t, Dc, Dc);

  gemm_bf16_kernel<1, 0><<<(Dc / 128) * (Mq / 128), 256, 0, stream>>>(
      Ab, Wq_t, bq, qb, Mq, Dc, Dc, nullptr);
  softmax_q_bf16_kernel<<<(Mq * 8) / 4, 256, 0, stream>>>(qb);

  // ---- kv path (reuses region R; Ab is dead now) ----
  ln_bf16_kernel<<<Mkv, 256, 0, stream>>>(xf, xfb, Lc, tnorm_g, tnorm_b);
  gemm_bf16_kernel<0, 0><<<(Dc / 128) * 20, 256, 0, stream>>>(
      xfb, Wk_t, bk, kbuf, Mkv, Lc, Dc, nullptr);
  gemm_bf16_kernel<0, 0><<<(Dc / 128) * 20, 256, 0, stream>>>(
      xfb, Wv_t, bv_, vbuf, Mkv, Lc, Dc, nullptr);
  softmax_k_kernel<<<(Bc * Dc) / 256, 256, 0, stream>>>(kbuf);
  attn_einsum_kernel<<<Bc * 8, 256, 0, stream>>>(kbuf, vbuf, attnb);

  // ---- FiLM params ----
  gemm_emb_kernel<<<dim3((2 * Dc) / 128, 1), 256, 0, stream>>>(
      emb, emb_W, emb_b, ssb, Bc, TEDc, 2 * Dc);

  // ---- y = q @ attn (in place over qb), LN+mod+SiLU (in place), final GEMM ----
  y_bf16_kernel<<<dim3(Tc / 64, Bc * 8), 256, 0, stream>>>(qb, attnb);
  ln_mod_silu_bf16_kernel<<<Mq, 256, 0, stream>>>(qb, ssb, onorm_g, onorm_b);
  gemm_bf16_kernel<0, 1><<<(Dc / 128) * (Mq / 128), 256, 0, stream>>>(
      qb, Wo_t, bo, out, Mq, Dc, Dc, x);
}

// Round 3
// 601.129 us; speedup vs baseline: 5.1380x; 1.9027x over previous
//
#include <hip/hip_runtime.h>
#include <hip/hip_bf16.h>
#include <math.h>

namespace {

constexpr int Bc  = 32;
constexpr int Tc  = 1024;
constexpr int Dc  = 1024;
constexpr int Nt  = 77;
constexpr int Lc  = 768;
constexpr int HDc = 128;
constexpr int TEDc = 2048;
constexpr float EPSc = 1e-5f;

typedef __attribute__((ext_vector_type(8))) short bf16x8;
typedef __attribute__((ext_vector_type(4))) float f32x4;

__device__ __forceinline__ float silu_f(float x) { return x / (1.f + __expf(-x)); }

__device__ __forceinline__ unsigned short f2bf(float f) {
  unsigned u = __float_as_uint(f);
  return (unsigned short)((u + 0x7fffu + ((u >> 16) & 1u)) >> 16);
}
__device__ __forceinline__ float bf2f(unsigned short h) {
  return __uint_as_float(((unsigned)h) << 16);
}

__device__ __forceinline__ void gload16(const void* g, void* l) {
  __builtin_amdgcn_global_load_lds((const __attribute__((address_space(1))) void*)g,
                                   (__attribute__((address_space(3))) void*)l, 16, 0, 0);
}

// ---------- fused LayerNorm -> bf16 matrix (one block per row) --------------------------
__global__ __launch_bounds__(256) void ln_bf16_kernel(
    const float* __restrict__ src, unsigned short* __restrict__ dst, int cols,
    const float* __restrict__ g, const float* __restrict__ b)
{
  const int row = blockIdx.x;
  const float* p = src + (size_t)row * cols;
  const int c = threadIdx.x * 4;
  float4 v = make_float4(0.f, 0.f, 0.f, 0.f);
  if (c < cols) v = *reinterpret_cast<const float4*>(p + c);
  float s  = v.x + v.y + v.z + v.w;
  float sq = v.x * v.x + v.y * v.y + v.z * v.z + v.w * v.w;
  __shared__ float red[2][4];
  __shared__ float mr[2];
  for (int o = 32; o > 0; o >>= 1) { s += __shfl_down(s, o); sq += __shfl_down(sq, o); }
  const int wid = threadIdx.x >> 6, lane = threadIdx.x & 63;
  if (lane == 0) { red[0][wid] = s; red[1][wid] = sq; }
  __syncthreads();
  if (threadIdx.x == 0) {
    const float S  = red[0][0] + red[0][1] + red[0][2] + red[0][3];
    const float SQ = red[1][0] + red[1][1] + red[1][2] + red[1][3];
    const float mean = S / cols;
    const float var  = SQ / cols - mean * mean;
    mr[0] = mean; mr[1] = rsqrtf(var + EPSc);
  }
  __syncthreads();
  if (c < cols) {
    const float mean = mr[0], rstd = mr[1];
    ushort4 o;
    o.x = f2bf((v.x - mean) * rstd * g[c + 0] + b[c + 0]);
    o.y = f2bf((v.y - mean) * rstd * g[c + 1] + b[c + 1]);
    o.z = f2bf((v.z - mean) * rstd * g[c + 2] + b[c + 2]);
    o.w = f2bf((v.w - mean) * rstd * g[c + 3] + b[c + 3]);
    *reinterpret_cast<ushort4*>(dst + (size_t)row * cols + c) = o;
  }
}

// ---------- transpose-convert W[K][N] f32 -> Wt[N][K] bf16 ------------------------------
__global__ __launch_bounds__(256) void convT_bf16_kernel(
    const float* __restrict__ W, unsigned short* __restrict__ Wt, int K, int N)
{
  __shared__ float t[32][33];
  const int n0 = blockIdx.x * 32, k0 = blockIdx.y * 32;
  const int tx = threadIdx.x & 31, ty = threadIdx.x >> 5;   // ty 0..7
  #pragma unroll
  for (int dy = 0; dy < 32; dy += 8)
    t[ty + dy][tx] = W[(size_t)(k0 + ty + dy) * N + n0 + tx];
  __syncthreads();
  #pragma unroll
  for (int dy = 0; dy < 32; dy += 8)
    Wt[(size_t)(n0 + ty + dy) * K + k0 + tx] = f2bf(t[tx][ty + dy]);
}

// ---------- bf16 MFMA GEMM: C[M][N] = A[M][K] @ Bt[N][K]^T + bias (+xres) ---------------
template<int OUTBF16, int ADDRES>
__global__ __launch_bounds__(256) void gemm_bf16_kernel(
    const unsigned short* __restrict__ A, const unsigned short* __restrict__ Bt,
    const float* __restrict__ bias, void* __restrict__ Cout,
    int M, int K, int N, const float* __restrict__ xres)
{
  __shared__ unsigned short As[128 * 32];
  __shared__ unsigned short Bs[128 * 32];
  const int tid = threadIdx.x, wid = tid >> 6, lane = tid & 63;
  const int ntx = N >> 7;
  const int bid = blockIdx.x, nwg = gridDim.x;
  int swz = bid;
  if ((nwg & 7) == 0) { const int cpx = nwg >> 3; swz = (bid & 7) * cpx + (bid >> 3); }
  const int bx = swz % ntx, by = swz / ntx;
  const int bm0 = by << 7, bn0 = bx << 7;
  const int wr = wid >> 1, wc = wid & 1, lhi = lane >> 4, llo = lane & 15;

  const int srow = lane >> 2;
  const int scol = (lane & 3) * 8;
  int ar0 = bm0 + wid * 32 + srow;
  int ar1 = ar0 + 16;
  if (ar0 >= M) ar0 = M - 1;
  if (ar1 >= M) ar1 = M - 1;
  const int br0 = bn0 + wid * 32 + srow;
  const int br1 = br0 + 16;
  const unsigned short* Ag0 = A  + (size_t)ar0 * K + scol;
  const unsigned short* Ag1 = A  + (size_t)ar1 * K + scol;
  const unsigned short* Bg0 = Bt + (size_t)br0 * K + scol;
  const unsigned short* Bg1 = Bt + (size_t)br1 * K + scol;
  unsigned short* Al0 = &As[(wid * 2 + 0) * 512];
  unsigned short* Al1 = &As[(wid * 2 + 1) * 512];
  unsigned short* Bl0 = &Bs[(wid * 2 + 0) * 512];
  unsigned short* Bl1 = &Bs[(wid * 2 + 1) * 512];

  const unsigned short* afb = &As[(wr * 64 + llo) * 32 + lhi * 8];
  const unsigned short* bfb = &Bs[(wc * 64 + llo) * 32 + lhi * 8];

  f32x4 acc[4][4] = {};

  for (int k0 = 0; k0 < K; k0 += 32) {
    gload16(Ag0 + k0, Al0);
    gload16(Ag1 + k0, Al1);
    gload16(Bg0 + k0, Bl0);
    gload16(Bg1 + k0, Bl1);
    __syncthreads();
    bf16x8 a_[4], b_[4];
    #pragma unroll
    for (int mi = 0; mi < 4; mi++) a_[mi] = *(const bf16x8*)(afb + mi * 512);
    #pragma unroll
    for (int ni = 0; ni < 4; ni++) b_[ni] = *(const bf16x8*)(bfb + ni * 512);
    #pragma unroll
    for (int mi = 0; mi < 4; mi++)
      #pragma unroll
      for (int ni = 0; ni < 4; ni++)
        acc[mi][ni] = __builtin_amdgcn_mfma_f32_16x16x32_bf16(a_[mi], b_[ni], acc[mi][ni], 0, 0, 0);
    __syncthreads();
  }

  #pragma unroll
  for (int mi = 0; mi < 4; mi++) {
    #pragma unroll
    for (int ni = 0; ni < 4; ni++) {
      const int col = bn0 + wc * 64 + ni * 16 + llo;
      const float bs = bias[col];
      #pragma unroll
      for (int r = 0; r < 4; r++) {
        const int row = bm0 + wr * 64 + mi * 16 + lhi * 4 + r;
        if (row < M) {
          float v = acc[mi][ni][r] + bs;
          if (ADDRES) v += xres[(size_t)row * N + col];
          if (OUTBF16) ((unsigned short*)Cout)[(size_t)row * N + col] = f2bf(v);
          else         ((float*)Cout)[(size_t)row * N + col] = v;
        }
      }
    }
  }
}

// ---------- softmax over head_dim (128 bf16), one wave per segment ----------------------
__global__ void softmax_q_bf16_kernel(unsigned short* __restrict__ q) {
  const int seg = blockIdx.x * 4 + (threadIdx.x >> 6);
  const int lane = threadIdx.x & 63;
  unsigned short* p = q + (size_t)seg * HDc + lane * 2;
  ushort2 u = *reinterpret_cast<const ushort2*>(p);
  float v0 = bf2f(u.x), v1 = bf2f(u.y);
  float m = fmaxf(v0, v1);
  for (int o = 32; o > 0; o >>= 1) m = fmaxf(m, __shfl_xor(m, o));
  float e0 = __expf(v0 - m), e1 = __expf(v1 - m);
  float ssum = e0 + e1;
  for (int o = 32; o > 0; o >>= 1) ssum += __shfl_xor(ssum, o);
  const float inv = 1.f / ssum;
  ushort2 o2; o2.x = f2bf(e0 * inv); o2.y = f2bf(e1 * inv);
  *reinterpret_cast<ushort2*>(p) = o2;
}

// ---------- softmax over N (=77) for each (b, d) column (fp32) --------------------------
__global__ void softmax_k_kernel(float* __restrict__ k) {
  const int idx = blockIdx.x * blockDim.x + threadIdx.x;  // b*D + d
  const int b = idx >> 10, d = idx & 1023;
  float* p = k + (size_t)b * Nt * Dc + d;
  float m = -1e30f;
  for (int n = 0; n < Nt; n++) m = fmaxf(m, p[(size_t)n * Dc]);
  float s = 0.f;
  for (int n = 0; n < Nt; n++) s += __expf(p[(size_t)n * Dc] - m);
  const float inv = 1.f / s;
  for (int n = 0; n < Nt; n++) p[(size_t)n * Dc] = __expf(p[(size_t)n * Dc] - m) * inv;
}

// ---------- attnT[b,h][dl][dd] = sum_n v[b,n,h,dl] * k[b,n,h,dd]  (bf16 out) ------------
__global__ __launch_bounds__(256) void attn_einsum_kernel(
    const float* __restrict__ k, const float* __restrict__ v,
    unsigned short* __restrict__ attnT) {
  const int bh = blockIdx.x;
  const int b = bh >> 3, h = bh & 7;
  __shared__ float ks[Nt][HDc];
  __shared__ float vs[Nt][HDc];
  const float* kb = k + (size_t)b * Nt * Dc + h * HDc;
  const float* vb = v + (size_t)b * Nt * Dc + h * HDc;
  for (int i = threadIdx.x; i < Nt * HDc; i += 256) {
    const int n = i >> 7, d = i & 127;
    ks[n][d] = kb[(size_t)n * Dc + d];
    vs[n][d] = vb[(size_t)n * Dc + d];
  }
  __syncthreads();
  const int tx = threadIdx.x & 15, ty = threadIdx.x >> 4;
  float acc[8][8] = {};
  for (int n = 0; n < Nt; n++) {
    float a[8], w[8];
    #pragma unroll
    for (int i = 0; i < 8; i++) a[i] = vs[n][ty + 16 * i];   // dl
    #pragma unroll
    for (int j = 0; j < 8; j++) w[j] = ks[n][tx + 16 * j];   // dd
    #pragma unroll
    for (int i = 0; i < 8; i++)
      #pragma unroll
      for (int j = 0; j < 8; j++)
        acc[i][j] += a[i] * w[j];
  }
  unsigned short* ab = attnT + (size_t)bh * HDc * HDc;
  #pragma unroll
  for (int i = 0; i < 8; i++)
    #pragma unroll
    for (int j = 0; j < 8; j++)
      ab[(size_t)(ty + 16 * i) * HDc + tx + 16 * j] = f2bf(acc[i][j]);
}

// ---------- y = q @ attn per (b,h), MFMA, in place over q (bf16) ------------------------
// C[t][l] = sum_d q[t][d] * attnT[l][d] ; per block: 128 t-rows x 128 l-cols, K=128
__global__ __launch_bounds__(256) void y_mfma_kernel(
    unsigned short* __restrict__ q, const unsigned short* __restrict__ attnT)
{
  __shared__ unsigned short As[128 * 32];
  __shared__ unsigned short Bs[128 * 32];
  const int tid = threadIdx.x, wid = tid >> 6, lane = tid & 63;
  const int bh = blockIdx.y, b = bh >> 3, h = bh & 7;
  const int bm0 = blockIdx.x << 7;          // t offset within this (b,h) slice
  const int wr = wid >> 1, wc = wid & 1, lhi = lane >> 4, llo = lane & 15;

  unsigned short* Abase = q + ((size_t)b * Tc) * Dc + h * HDc;   // lda = Dc
  const unsigned short* Btb = attnT + (size_t)bh * HDc * HDc;    // ldb = HDc

  const int srow = lane >> 2;
  const int scol = (lane & 3) * 8;
  const int ar0 = bm0 + wid * 32 + srow, ar1 = ar0 + 16;
  const int br0 = wid * 32 + srow,       br1 = br0 + 16;
  const unsigned short* Ag0 = Abase + (size_t)ar0 * Dc + scol;
  const unsigned short* Ag1 = Abase + (size_t)ar1 * Dc + scol;
  const unsigned short* Bg0 = Btb + (size_t)br0 * HDc + scol;
  const unsigned short* Bg1 = Btb + (size_t)br1 * HDc + scol;
  unsigned short* Al0 = &As[(wid * 2 + 0) * 512];
  unsigned short* Al1 = &As[(wid * 2 + 1) * 512];
  unsigned short* Bl0 = &Bs[(wid * 2 + 0) * 512];
  unsigned short* Bl1 = &Bs[(wid * 2 + 1) * 512];
  const unsigned short* afb = &As[(wr * 64 + llo) * 32 + lhi * 8];
  const unsigned short* bfb = &Bs[(wc * 64 + llo) * 32 + lhi * 8];

  f32x4 acc[4][4] = {};
  for (int k0 = 0; k0 < HDc; k0 += 32) {
    gload16(Ag0 + k0, Al0);
    gload16(Ag1 + k0, Al1);
    gload16(Bg0 + k0, Bl0);
    gload16(Bg1 + k0, Bl1);
    __syncthreads();
    bf16x8 a_[4], b_[4];
    #pragma unroll
    for (int mi = 0; mi < 4; mi++) a_[mi] = *(const bf16x8*)(afb + mi * 512);
    #pragma unroll
    for (int ni = 0; ni < 4; ni++) b_[ni] = *(const bf16x8*)(bfb + ni * 512);
    #pragma unroll
    for (int mi = 0; mi < 4; mi++)
      #pragma unroll
      for (int ni = 0; ni < 4; ni++)
        acc[mi][ni] = __builtin_amdgcn_mfma_f32_16x16x32_bf16(a_[mi], b_[ni], acc[mi][ni], 0, 0, 0);
    __syncthreads();
  }
  #pragma unroll
  for (int mi = 0; mi < 4; mi++) {
    #pragma unroll
    for (int ni = 0; ni < 4; ni++) {
      const int col = wc * 64 + ni * 16 + llo;
      #pragma unroll
      for (int r = 0; r < 4; r++) {
        const int row = bm0 + wr * 64 + mi * 16 + lhi * 4 + r;
        Abase[(size_t)row * Dc + col] = f2bf(acc[mi][ni][r]);
      }
    }
  }
}

// ---------- LN(y)*(1+scale)+shift -> SiLU, in place (bf16) ------------------------------
__global__ __launch_bounds__(256) void ln_mod_silu_bf16_kernel(
    unsigned short* __restrict__ y, const float* __restrict__ ss,
    const float* __restrict__ g, const float* __restrict__ bvec) {
  const int row = blockIdx.x;          // b*T + t
  const int b = row >> 10;
  unsigned short* p = y + (size_t)row * Dc;
  const int c = threadIdx.x * 4;
  ushort4 u = *reinterpret_cast<const ushort4*>(p + c);
  float vv[4] = {bf2f(u.x), bf2f(u.y), bf2f(u.z), bf2f(u.w)};
  float s  = vv[0] + vv[1] + vv[2] + vv[3];
  float sq = vv[0]*vv[0] + vv[1]*vv[1] + vv[2]*vv[2] + vv[3]*vv[3];
  __shared__ float red[2][4];
  __shared__ float mr[2];
  for (int o = 32; o > 0; o >>= 1) { s += __shfl_down(s, o); sq += __shfl_down(sq, o); }
  const int wid = threadIdx.x >> 6, lane = threadIdx.x & 63;
  if (lane == 0) { red[0][wid] = s; red[1][wid] = sq; }
  __syncthreads();
  if (threadIdx.x == 0) {
    const float S  = red[0][0] + red[0][1] + red[0][2] + red[0][3];
    const float SQ = red[1][0] + red[1][1] + red[1][2] + red[1][3];
    const float mean = S / Dc;
    const float var = SQ / Dc - mean * mean;
    mr[0] = mean; mr[1] = rsqrtf(var + EPSc);
  }
  __syncthreads();
  const float mean = mr[0], rstd = mr[1];
  const float* ssb = ss + (size_t)b * 2 * Dc;
  ushort4 o;
  float t0 = (vv[0] - mean) * rstd * g[c + 0] + bvec[c + 0];
  float t1 = (vv[1] - mean) * rstd * g[c + 1] + bvec[c + 1];
  float t2 = (vv[2] - mean) * rstd * g[c + 2] + bvec[c + 2];
  float t3 = (vv[3] - mean) * rstd * g[c + 3] + bvec[c + 3];
  o.x = f2bf(silu_f(t0 * (1.f + ssb[c + 0]) + ssb[Dc + c + 0]));
  o.y = f2bf(silu_f(t1 * (1.f + ssb[c + 1]) + ssb[Dc + c + 1]));
  o.z = f2bf(silu_f(t2 * (1.f + ssb[c + 2]) + ssb[Dc + c + 2]));
  o.w = f2bf(silu_f(t3 * (1.f + ssb[c + 3]) + ssb[Dc + c + 3]));
  *reinterpret_cast<ushort4*>(p + c) = o;
}

// ---------- emb projection: silu precompute, split-K partial GEMM, reduce ---------------
__global__ __launch_bounds__(256) void silu_emb_kernel(
    const float* __restrict__ emb, float* __restrict__ sile) {
  const int i = (blockIdx.x * 256 + threadIdx.x) * 4;
  float4 v = *reinterpret_cast<const float4*>(emb + i);
  v.x = silu_f(v.x); v.y = silu_f(v.y); v.z = silu_f(v.z); v.w = silu_f(v.w);
  *reinterpret_cast<float4*>(sile + i) = v;
}

// grid: (8 col-blocks, 32 k-splits). part[split][32][2048]
__global__ __launch_bounds__(256) void emb_part_kernel(
    const float* __restrict__ sile, const float* __restrict__ W,
    float* __restrict__ part) {
  const int split = blockIdx.y;
  const int n = blockIdx.x * 256 + threadIdx.x;
  const int k0 = split * 64;
  const float* se = sile + k0;                       // wave-uniform accesses -> s_load
  const float* Wp = W + (size_t)k0 * (2 * Dc) + n;
  float acc[32] = {};
  for (int kk = 0; kk < 64; kk++) {
    const float w = Wp[(size_t)kk * (2 * Dc)];
    #pragma unroll
    for (int m = 0; m < 32; m++)
      acc[m] = fmaf(se[m * TEDc + kk], w, acc[m]);
  }
  float* pp = part + (size_t)split * 32 * (2 * Dc) + n;
  #pragma unroll
  for (int m = 0; m < 32; m++) pp[(size_t)m * (2 * Dc)] = acc[m];
}

__global__ __launch_bounds__(256) void emb_reduce_kernel(
    const float* __restrict__ part, const float* __restrict__ bias,
    float* __restrict__ ssb) {
  const int i = blockIdx.x * 256 + threadIdx.x;      // 0..65535
  const int n = i & (2 * Dc - 1);
  float s = bias[n];
  #pragma unroll 8
  for (int sp = 0; sp < 32; sp++) s += part[(size_t)sp * 32 * (2 * Dc) + i];
  ssb[i] = s;
}

}  // namespace

extern "C" void kernel_launch(void* const* d_in, const int* in_sizes, int n_in,
                              void* d_out, int out_size, void* d_ws, size_t ws_size,
                              hipStream_t stream) {
  const float* x       = (const float*)d_in[0];
  const float* xf      = (const float*)d_in[1];
  const float* emb     = (const float*)d_in[2];
  const float* norm_g  = (const float*)d_in[3];
  const float* norm_b  = (const float*)d_in[4];
  const float* tnorm_g = (const float*)d_in[5];
  const float* tnorm_b = (const float*)d_in[6];
  const float* Wq      = (const float*)d_in[7];
  const float* bq      = (const float*)d_in[8];
  const float* Wk      = (const float*)d_in[9];
  const float* bk      = (const float*)d_in[10];
  const float* Wv      = (const float*)d_in[11];
  const float* bv_     = (const float*)d_in[12];
  const float* emb_W   = (const float*)d_in[13];
  const float* emb_b   = (const float*)d_in[14];
  const float* onorm_g = (const float*)d_in[15];
  const float* onorm_b = (const float*)d_in[16];
  const float* Wo      = (const float*)d_in[17];
  const float* bo      = (const float*)d_in[18];
  float* out = (float*)d_out;

  char* ws = (char*)d_ws;
  unsigned short* Ab = (unsigned short*)ws;                       // [32768][1024] bf16
  char* R = ws;                                                   // aliased after q-GEMM
  unsigned short* qb   = (unsigned short*)(ws + 67108864);        // [32768][1024] bf16
  unsigned short* Wq_t = (unsigned short*)(ws + 134217728);
  unsigned short* Wk_t = (unsigned short*)(ws + 136314880);
  unsigned short* Wv_t = (unsigned short*)(ws + 137887744);
  unsigned short* Wo_t = (unsigned short*)(ws + 139460608);
  float*          ssb  = (float*)(ws + 141557760);                // [32][2048]
  float*          sile = (float*)(ws + 141819904);                // [32][2048]
  float*          part = (float*)(ws + 142082048);                // [32][32][2048]
  // kv-phase aliases inside R (stream-serial after q-GEMM consumed Ab):
  unsigned short* xfb   = (unsigned short*)(R);                   // [2464][768] bf16
  float*          kbuf  = (float*)(R + 3784704);                  // [2464][1024] f32
  float*          vbuf  = (float*)(R + 13877248);                 // [2464][1024] f32
  unsigned short* attnT = (unsigned short*)(R + 23969792);        // [256][128][128] bf16

  const int Mq  = Bc * Tc;   // 32768
  const int Mkv = Bc * Nt;   // 2464

  // ---- q path ----
  ln_bf16_kernel<<<Mq, 256, 0, stream>>>(x, Ab, Dc, norm_g, norm_b);
  convT_bf16_kernel<<<dim3(Dc / 32, Dc / 32), 256, 0, stream>>>(Wq, Wq_t, Dc, Dc);
  convT_bf16_kernel<<<dim3(Dc / 32, Lc / 32), 256, 0, stream>>>(Wk, Wk_t, Lc, Dc);
  convT_bf16_kernel<<<dim3(Dc / 32, Lc / 32), 256, 0, stream>>>(Wv, Wv_t, Lc, Dc);
  convT_bf16_kernel<<<dim3(Dc / 32, Dc / 32), 256, 0, stream>>>(Wo, Wo_t, Dc, Dc);

  gemm_bf16_kernel<1, 0><<<(Dc / 128) * (Mq / 128), 256, 0, stream>>>(
      Ab, Wq_t, bq, qb, Mq, Dc, Dc, nullptr);
  softmax_q_bf16_kernel<<<(Mq * 8) / 4, 256, 0, stream>>>(qb);

  // ---- kv path (reuses region R) ----
  ln_bf16_kernel<<<Mkv, 256, 0, stream>>>(xf, xfb, Lc, tnorm_g, tnorm_b);
  gemm_bf16_kernel<0, 0><<<(Dc / 128) * 20, 256, 0, stream>>>(
      xfb, Wk_t, bk, kbuf, Mkv, Lc, Dc, nullptr);
  gemm_bf16_kernel<0, 0><<<(Dc / 128) * 20, 256, 0, stream>>>(
      xfb, Wv_t, bv_, vbuf, Mkv, Lc, Dc, nullptr);
  softmax_k_kernel<<<(Bc * Dc) / 256, 256, 0, stream>>>(kbuf);
  attn_einsum_kernel<<<Bc * 8, 256, 0, stream>>>(kbuf, vbuf, attnT);

  // ---- FiLM params: split-K ----
  silu_emb_kernel<<<(Bc * TEDc) / 1024, 256, 0, stream>>>(emb, sile);
  emb_part_kernel<<<dim3(8, 32), 256, 0, stream>>>(sile, emb_W, part);
  emb_reduce_kernel<<<(Bc * 2 * Dc) / 256, 256, 0, stream>>>(part, emb_b, ssb);

  // ---- y = q @ attn (MFMA, in place), LN+mod+SiLU, final GEMM + residual ----
  y_mfma_kernel<<<dim3(Tc / 128, Bc * 8), 256, 0, stream>>>(qb, attnT);
  ln_mod_silu_bf16_kernel<<<Mq, 256, 0, stream>>>(qb, ssb, onorm_g, onorm_b);
  gemm_bf16_kernel<0, 1><<<(Dc / 128) * (Mq / 128), 256, 0, stream>>>(
      qb, Wo_t, bo, out, Mq, Dc, Dc, x);
}

// Round 4
// 565.816 us; speedup vs baseline: 5.4586x; 1.0624x over previous
//
#include <hip/hip_runtime.h>
#include <hip/hip_bf16.h>
#include <math.h>

namespace {

constexpr int Bc  = 32;
constexpr int Tc  = 1024;
constexpr int Dc  = 1024;
constexpr int Nt  = 77;
constexpr int Lc  = 768;
constexpr int HDc = 128;
constexpr int TEDc = 2048;
constexpr float EPSc = 1e-5f;

typedef __attribute__((ext_vector_type(8))) short bf16x8;
typedef __attribute__((ext_vector_type(4))) float f32x4;

__device__ __forceinline__ float silu_f(float x) { return x / (1.f + __expf(-x)); }

__device__ __forceinline__ unsigned short f2bf(float f) {
  unsigned u = __float_as_uint(f);
  return (unsigned short)((u + 0x7fffu + ((u >> 16) & 1u)) >> 16);
}
__device__ __forceinline__ float bf2f(unsigned short h) {
  return __uint_as_float(((unsigned)h) << 16);
}

__device__ __forceinline__ void gload16(const void* g, void* l) {
  __builtin_amdgcn_global_load_lds((const __attribute__((address_space(1))) void*)g,
                                   (__attribute__((address_space(3))) void*)l, 16, 0, 0);
}

// ---------- fused LayerNorm -> bf16 matrix (one block per row) --------------------------
__global__ __launch_bounds__(256) void ln_bf16_kernel(
    const float* __restrict__ src, unsigned short* __restrict__ dst, int cols,
    const float* __restrict__ g, const float* __restrict__ b)
{
  const int row = blockIdx.x;
  const float* p = src + (size_t)row * cols;
  const int c = threadIdx.x * 4;
  float4 v = make_float4(0.f, 0.f, 0.f, 0.f);
  if (c < cols) v = *reinterpret_cast<const float4*>(p + c);
  float s  = v.x + v.y + v.z + v.w;
  float sq = v.x * v.x + v.y * v.y + v.z * v.z + v.w * v.w;
  __shared__ float red[2][4];
  __shared__ float mr[2];
  for (int o = 32; o > 0; o >>= 1) { s += __shfl_down(s, o); sq += __shfl_down(sq, o); }
  const int wid = threadIdx.x >> 6, lane = threadIdx.x & 63;
  if (lane == 0) { red[0][wid] = s; red[1][wid] = sq; }
  __syncthreads();
  if (threadIdx.x == 0) {
    const float S  = red[0][0] + red[0][1] + red[0][2] + red[0][3];
    const float SQ = red[1][0] + red[1][1] + red[1][2] + red[1][3];
    const float mean = S / cols;
    const float var  = SQ / cols - mean * mean;
    mr[0] = mean; mr[1] = rsqrtf(var + EPSc);
  }
  __syncthreads();
  if (c < cols) {
    const float mean = mr[0], rstd = mr[1];
    ushort4 o;
    o.x = f2bf((v.x - mean) * rstd * g[c + 0] + b[c + 0]);
    o.y = f2bf((v.y - mean) * rstd * g[c + 1] + b[c + 1]);
    o.z = f2bf((v.z - mean) * rstd * g[c + 2] + b[c + 2]);
    o.w = f2bf((v.w - mean) * rstd * g[c + 3] + b[c + 3]);
    *reinterpret_cast<ushort4*>(dst + (size_t)row * cols + c) = o;
  }
}

// ---------- transpose-convert W[K][N] f32 -> Wt[N][K] bf16 ------------------------------
__global__ __launch_bounds__(256) void convT_bf16_kernel(
    const float* __restrict__ W, unsigned short* __restrict__ Wt, int K, int N)
{
  __shared__ float t[32][33];
  const int n0 = blockIdx.x * 32, k0 = blockIdx.y * 32;
  const int tx = threadIdx.x & 31, ty = threadIdx.x >> 5;   // ty 0..7
  #pragma unroll
  for (int dy = 0; dy < 32; dy += 8)
    t[ty + dy][tx] = W[(size_t)(k0 + ty + dy) * N + n0 + tx];
  __syncthreads();
  #pragma unroll
  for (int dy = 0; dy < 32; dy += 8)
    Wt[(size_t)(n0 + ty + dy) * K + k0 + tx] = f2bf(t[tx][ty + dy]);
}

// ---------- bf16 MFMA GEMM, 2-phase double-buffered --------------------------------------
// C[M][N] = A[M][K] @ Bt[N][K]^T + bias (+xres)
template<int OUTBF16, int ADDRES>
__global__ __launch_bounds__(256) void gemm_bf16_kernel(
    const unsigned short* __restrict__ A, const unsigned short* __restrict__ Bt,
    const float* __restrict__ bias, void* __restrict__ Cout,
    int M, int K, int N, const float* __restrict__ xres)
{
  __shared__ unsigned short As[2][4096];
  __shared__ unsigned short Bs[2][4096];
  const int tid = threadIdx.x, wid = tid >> 6, lane = tid & 63;
  const int ntx = N >> 7;
  const int bid = blockIdx.x, nwg = gridDim.x;
  int swz = bid;
  if ((nwg & 7) == 0) { const int cpx = nwg >> 3; swz = (bid & 7) * cpx + (bid >> 3); }
  const int bx = swz % ntx, by = swz / ntx;
  const int bm0 = by << 7, bn0 = bx << 7;
  const int wr = wid >> 1, wc = wid & 1, lhi = lane >> 4, llo = lane & 15;

  const int srow = lane >> 2;
  const int scol = (lane & 3) * 8;
  int ar0 = bm0 + wid * 32 + srow;
  int ar1 = ar0 + 16;
  if (ar0 >= M) ar0 = M - 1;
  if (ar1 >= M) ar1 = M - 1;
  const int br0 = bn0 + wid * 32 + srow;
  const int br1 = br0 + 16;
  const unsigned short* Ag0 = A  + (size_t)ar0 * K + scol;
  const unsigned short* Ag1 = A  + (size_t)ar1 * K + scol;
  const unsigned short* Bg0 = Bt + (size_t)br0 * K + scol;
  const unsigned short* Bg1 = Bt + (size_t)br1 * K + scol;
  const int lc0 = (wid * 2 + 0) * 512;      // this wave's LDS chunk offsets (elements)
  const int lc1 = (wid * 2 + 1) * 512;
  const int aoff = (wr * 64 + llo) * 32 + lhi * 8;
  const int boff = (wc * 64 + llo) * 32 + lhi * 8;

  f32x4 acc[4][4] = {};

  // prologue: stage tile 0 into buffer 0
  gload16(Ag0, &As[0][lc0]);
  gload16(Ag1, &As[0][lc1]);
  gload16(Bg0, &Bs[0][lc0]);
  gload16(Bg1, &Bs[0][lc1]);
  __syncthreads();

  int cur = 0;
  for (int k0 = 32; k0 < K; k0 += 32) {
    // issue next-tile loads (in flight during compute below)
    const int nxt = cur ^ 1;
    gload16(Ag0 + k0, &As[nxt][lc0]);
    gload16(Ag1 + k0, &As[nxt][lc1]);
    gload16(Bg0 + k0, &Bs[nxt][lc0]);
    gload16(Bg1 + k0, &Bs[nxt][lc1]);
    // compute current tile
    bf16x8 a_[4], b_[4];
    #pragma unroll
    for (int mi = 0; mi < 4; mi++) a_[mi] = *(const bf16x8*)(&As[cur][aoff + mi * 512]);
    #pragma unroll
    for (int ni = 0; ni < 4; ni++) b_[ni] = *(const bf16x8*)(&Bs[cur][boff + ni * 512]);
    #pragma unroll
    for (int mi = 0; mi < 4; mi++)
      #pragma unroll
      for (int ni = 0; ni < 4; ni++)
        acc[mi][ni] = __builtin_amdgcn_mfma_f32_16x16x32_bf16(a_[mi], b_[ni], acc[mi][ni], 0, 0, 0);
    __syncthreads();    // drains vmcnt (next tile ready) + protects buf reuse
    cur = nxt;
  }
  // epilogue tile
  {
    bf16x8 a_[4], b_[4];
    #pragma unroll
    for (int mi = 0; mi < 4; mi++) a_[mi] = *(const bf16x8*)(&As[cur][aoff + mi * 512]);
    #pragma unroll
    for (int ni = 0; ni < 4; ni++) b_[ni] = *(const bf16x8*)(&Bs[cur][boff + ni * 512]);
    #pragma unroll
    for (int mi = 0; mi < 4; mi++)
      #pragma unroll
      for (int ni = 0; ni < 4; ni++)
        acc[mi][ni] = __builtin_amdgcn_mfma_f32_16x16x32_bf16(a_[mi], b_[ni], acc[mi][ni], 0, 0, 0);
  }

  #pragma unroll
  for (int mi = 0; mi < 4; mi++) {
    #pragma unroll
    for (int ni = 0; ni < 4; ni++) {
      const int col = bn0 + wc * 64 + ni * 16 + llo;
      const float bs = bias[col];
      #pragma unroll
      for (int r = 0; r < 4; r++) {
        const int row = bm0 + wr * 64 + mi * 16 + lhi * 4 + r;
        if (row < M) {
          float v = acc[mi][ni][r] + bs;
          if (ADDRES) v += xres[(size_t)row * N + col];
          if (OUTBF16) ((unsigned short*)Cout)[(size_t)row * N + col] = f2bf(v);
          else         ((float*)Cout)[(size_t)row * N + col] = v;
        }
      }
    }
  }
}

// ---------- softmax over head_dim (128 bf16), one wave per segment ----------------------
__global__ void softmax_q_bf16_kernel(unsigned short* __restrict__ q) {
  const int seg = blockIdx.x * 4 + (threadIdx.x >> 6);
  const int lane = threadIdx.x & 63;
  unsigned short* p = q + (size_t)seg * HDc + lane * 2;
  ushort2 u = *reinterpret_cast<const ushort2*>(p);
  float v0 = bf2f(u.x), v1 = bf2f(u.y);
  float m = fmaxf(v0, v1);
  for (int o = 32; o > 0; o >>= 1) m = fmaxf(m, __shfl_xor(m, o));
  float e0 = __expf(v0 - m), e1 = __expf(v1 - m);
  float ssum = e0 + e1;
  for (int o = 32; o > 0; o >>= 1) ssum += __shfl_xor(ssum, o);
  const float inv = 1.f / ssum;
  ushort2 o2; o2.x = f2bf(e0 * inv); o2.y = f2bf(e1 * inv);
  *reinterpret_cast<ushort2*>(p) = o2;
}

// ---------- softmax over N (=77) for each (b, d) column (fp32) --------------------------
__global__ void softmax_k_kernel(float* __restrict__ k) {
  const int idx = blockIdx.x * blockDim.x + threadIdx.x;  // b*D + d
  const int b = idx >> 10, d = idx & 1023;
  float* p = k + (size_t)b * Nt * Dc + d;
  float m = -1e30f;
  for (int n = 0; n < Nt; n++) m = fmaxf(m, p[(size_t)n * Dc]);
  float s = 0.f;
  for (int n = 0; n < Nt; n++) s += __expf(p[(size_t)n * Dc] - m);
  const float inv = 1.f / s;
  for (int n = 0; n < Nt; n++) p[(size_t)n * Dc] = __expf(p[(size_t)n * Dc] - m) * inv;
}

// ---------- attnT[b,h][dl][dd] = sum_n v[b,n,h,dl] * k[b,n,h,dd]  (bf16 out) ------------
__global__ __launch_bounds__(256) void attn_einsum_kernel(
    const float* __restrict__ k, const float* __restrict__ v,
    unsigned short* __restrict__ attnT) {
  const int bh = blockIdx.x;
  const int b = bh >> 3, h = bh & 7;
  __shared__ float ks[Nt][HDc];
  __shared__ float vs[Nt][HDc];
  const float* kb = k + (size_t)b * Nt * Dc + h * HDc;
  const float* vb = v + (size_t)b * Nt * Dc + h * HDc;
  for (int i = threadIdx.x; i < Nt * HDc; i += 256) {
    const int n = i >> 7, d = i & 127;
    ks[n][d] = kb[(size_t)n * Dc + d];
    vs[n][d] = vb[(size_t)n * Dc + d];
  }
  __syncthreads();
  const int tx = threadIdx.x & 15, ty = threadIdx.x >> 4;
  float acc[8][8] = {};
  for (int n = 0; n < Nt; n++) {
    float a[8], w[8];
    #pragma unroll
    for (int i = 0; i < 8; i++) a[i] = vs[n][ty + 16 * i];   // dl
    #pragma unroll
    for (int j = 0; j < 8; j++) w[j] = ks[n][tx + 16 * j];   // dd
    #pragma unroll
    for (int i = 0; i < 8; i++)
      #pragma unroll
      for (int j = 0; j < 8; j++)
        acc[i][j] += a[i] * w[j];
  }
  unsigned short* ab = attnT + (size_t)bh * HDc * HDc;
  #pragma unroll
  for (int i = 0; i < 8; i++)
    #pragma unroll
    for (int j = 0; j < 8; j++)
      ab[(size_t)(ty + 16 * i) * HDc + tx + 16 * j] = f2bf(acc[i][j]);
}

// ---------- y = q @ attn per (b,h), MFMA 2-phase, in place over q (bf16) ----------------
__global__ __launch_bounds__(256) void y_mfma_kernel(
    unsigned short* __restrict__ q, const unsigned short* __restrict__ attnT)
{
  __shared__ unsigned short As[2][4096];
  __shared__ unsigned short Bs[2][4096];
  const int tid = threadIdx.x, wid = tid >> 6, lane = tid & 63;
  const int bh = blockIdx.y, b = bh >> 3, h = bh & 7;
  const int bm0 = blockIdx.x << 7;          // t offset within this (b,h) slice
  const int wr = wid >> 1, wc = wid & 1, lhi = lane >> 4, llo = lane & 15;

  unsigned short* Abase = q + ((size_t)b * Tc) * Dc + h * HDc;   // lda = Dc
  const unsigned short* Btb = attnT + (size_t)bh * HDc * HDc;    // ldb = HDc

  const int srow = lane >> 2;
  const int scol = (lane & 3) * 8;
  const int ar0 = bm0 + wid * 32 + srow, ar1 = ar0 + 16;
  const int br0 = wid * 32 + srow,       br1 = br0 + 16;
  const unsigned short* Ag0 = Abase + (size_t)ar0 * Dc + scol;
  const unsigned short* Ag1 = Abase + (size_t)ar1 * Dc + scol;
  const unsigned short* Bg0 = Btb + (size_t)br0 * HDc + scol;
  const unsigned short* Bg1 = Btb + (size_t)br1 * HDc + scol;
  const int lc0 = (wid * 2 + 0) * 512;
  const int lc1 = (wid * 2 + 1) * 512;
  const int aoff = (wr * 64 + llo) * 32 + lhi * 8;
  const int boff = (wc * 64 + llo) * 32 + lhi * 8;

  f32x4 acc[4][4] = {};

  gload16(Ag0, &As[0][lc0]);
  gload16(Ag1, &As[0][lc1]);
  gload16(Bg0, &Bs[0][lc0]);
  gload16(Bg1, &Bs[0][lc1]);
  __syncthreads();

  int cur = 0;
  for (int k0 = 32; k0 < HDc; k0 += 32) {
    const int nxt = cur ^ 1;
    gload16(Ag0 + k0, &As[nxt][lc0]);
    gload16(Ag1 + k0, &As[nxt][lc1]);
    gload16(Bg0 + k0, &Bs[nxt][lc0]);
    gload16(Bg1 + k0, &Bs[nxt][lc1]);
    bf16x8 a_[4], b_[4];
    #pragma unroll
    for (int mi = 0; mi < 4; mi++) a_[mi] = *(const bf16x8*)(&As[cur][aoff + mi * 512]);
    #pragma unroll
    for (int ni = 0; ni < 4; ni++) b_[ni] = *(const bf16x8*)(&Bs[cur][boff + ni * 512]);
    #pragma unroll
    for (int mi = 0; mi < 4; mi++)
      #pragma unroll
      for (int ni = 0; ni < 4; ni++)
        acc[mi][ni] = __builtin_amdgcn_mfma_f32_16x16x32_bf16(a_[mi], b_[ni], acc[mi][ni], 0, 0, 0);
    __syncthreads();
    cur = nxt;
  }
  {
    bf16x8 a_[4], b_[4];
    #pragma unroll
    for (int mi = 0; mi < 4; mi++) a_[mi] = *(const bf16x8*)(&As[cur][aoff + mi * 512]);
    #pragma unroll
    for (int ni = 0; ni < 4; ni++) b_[ni] = *(const bf16x8*)(&Bs[cur][boff + ni * 512]);
    #pragma unroll
    for (int mi = 0; mi < 4; mi++)
      #pragma unroll
      for (int ni = 0; ni < 4; ni++)
        acc[mi][ni] = __builtin_amdgcn_mfma_f32_16x16x32_bf16(a_[mi], b_[ni], acc[mi][ni], 0, 0, 0);
  }
  // all reads of this block's q-tile are done (A staged tiles cover k0=0..127 of the same
  // 128 rows this block writes); in-place write is safe per-block.
  #pragma unroll
  for (int mi = 0; mi < 4; mi++) {
    #pragma unroll
    for (int ni = 0; ni < 4; ni++) {
      const int col = wc * 64 + ni * 16 + llo;
      #pragma unroll
      for (int r = 0; r < 4; r++) {
        const int row = bm0 + wr * 64 + mi * 16 + lhi * 4 + r;
        Abase[(size_t)row * Dc + col] = f2bf(acc[mi][ni][r]);
      }
    }
  }
}

// ---------- LN(y)*(1+scale)+shift -> SiLU, in place (bf16) ------------------------------
__global__ __launch_bounds__(256) void ln_mod_silu_bf16_kernel(
    unsigned short* __restrict__ y, const float* __restrict__ ss,
    const float* __restrict__ g, const float* __restrict__ bvec) {
  const int row = blockIdx.x;          // b*T + t
  const int b = row >> 10;
  unsigned short* p = y + (size_t)row * Dc;
  const int c = threadIdx.x * 4;
  ushort4 u = *reinterpret_cast<const ushort4*>(p + c);
  float vv[4] = {bf2f(u.x), bf2f(u.y), bf2f(u.z), bf2f(u.w)};
  float s  = vv[0] + vv[1] + vv[2] + vv[3];
  float sq = vv[0]*vv[0] + vv[1]*vv[1] + vv[2]*vv[2] + vv[3]*vv[3];
  __shared__ float red[2][4];
  __shared__ float mr[2];
  for (int o = 32; o > 0; o >>= 1) { s += __shfl_down(s, o); sq += __shfl_down(sq, o); }
  const int wid = threadIdx.x >> 6, lane = threadIdx.x & 63;
  if (lane == 0) { red[0][wid] = s; red[1][wid] = sq; }
  __syncthreads();
  if (threadIdx.x == 0) {
    const float S  = red[0][0] + red[0][1] + red[0][2] + red[0][3];
    const float SQ = red[1][0] + red[1][1] + red[1][2] + red[1][3];
    const float mean = S / Dc;
    const float var = SQ / Dc - mean * mean;
    mr[0] = mean; mr[1] = rsqrtf(var + EPSc);
  }
  __syncthreads();
  const float mean = mr[0], rstd = mr[1];
  const float* ssb = ss + (size_t)b * 2 * Dc;
  ushort4 o;
  float t0 = (vv[0] - mean) * rstd * g[c + 0] + bvec[c + 0];
  float t1 = (vv[1] - mean) * rstd * g[c + 1] + bvec[c + 1];
  float t2 = (vv[2] - mean) * rstd * g[c + 2] + bvec[c + 2];
  float t3 = (vv[3] - mean) * rstd * g[c + 3] + bvec[c + 3];
  o.x = f2bf(silu_f(t0 * (1.f + ssb[c + 0]) + ssb[Dc + c + 0]));
  o.y = f2bf(silu_f(t1 * (1.f + ssb[c + 1]) + ssb[Dc + c + 1]));
  o.z = f2bf(silu_f(t2 * (1.f + ssb[c + 2]) + ssb[Dc + c + 2]));
  o.w = f2bf(silu_f(t3 * (1.f + ssb[c + 3]) + ssb[Dc + c + 3]));
  *reinterpret_cast<ushort4*>(p + c) = o;
}

// ---------- emb projection: silu precompute, split-K partial GEMM, reduce ---------------
__global__ __launch_bounds__(256) void silu_emb_kernel(
    const float* __restrict__ emb, float* __restrict__ sile) {
  const int i = (blockIdx.x * 256 + threadIdx.x) * 4;
  float4 v = *reinterpret_cast<const float4*>(emb + i);
  v.x = silu_f(v.x); v.y = silu_f(v.y); v.z = silu_f(v.z); v.w = silu_f(v.w);
  *reinterpret_cast<float4*>(sile + i) = v;
}

// grid: (8 col-blocks, 32 k-splits). part[split][32][2048]
__global__ __launch_bounds__(256) void emb_part_kernel(
    const float* __restrict__ sile, const float* __restrict__ W,
    float* __restrict__ part) {
  const int split = blockIdx.y;
  const int n = blockIdx.x * 256 + threadIdx.x;
  const int k0 = split * 64;
  const float* se = sile + k0;                       // wave-uniform accesses -> s_load
  const float* Wp = W + (size_t)k0 * (2 * Dc) + n;
  float acc[32] = {};
  for (int kk = 0; kk < 64; kk++) {
    const float w = Wp[(size_t)kk * (2 * Dc)];
    #pragma unroll
    for (int m = 0; m < 32; m++)
      acc[m] = fmaf(se[m * TEDc + kk], w, acc[m]);
  }
  float* pp = part + (size_t)split * 32 * (2 * Dc) + n;
  #pragma unroll
  for (int m = 0; m < 32; m++) pp[(size_t)m * (2 * Dc)] = acc[m];
}

__global__ __launch_bounds__(256) void emb_reduce_kernel(
    const float* __restrict__ part, const float* __restrict__ bias,
    float* __restrict__ ssb) {
  const int i = blockIdx.x * 256 + threadIdx.x;      // 0..65535
  const int n = i & (2 * Dc - 1);
  float s = bias[n];
  #pragma unroll 8
  for (int sp = 0; sp < 32; sp++) s += part[(size_t)sp * 32 * (2 * Dc) + i];
  ssb[i] = s;
}

}  // namespace

extern "C" void kernel_launch(void* const* d_in, const int* in_sizes, int n_in,
                              void* d_out, int out_size, void* d_ws, size_t ws_size,
                              hipStream_t stream) {
  const float* x       = (const float*)d_in[0];
  const float* xf      = (const float*)d_in[1];
  const float* emb     = (const float*)d_in[2];
  const float* norm_g  = (const float*)d_in[3];
  const float* norm_b  = (const float*)d_in[4];
  const float* tnorm_g = (const float*)d_in[5];
  const float* tnorm_b = (const float*)d_in[6];
  const float* Wq      = (const float*)d_in[7];
  const float* bq      = (const float*)d_in[8];
  const float* Wk      = (const float*)d_in[9];
  const float* bk      = (const float*)d_in[10];
  const float* Wv      = (const float*)d_in[11];
  const float* bv_     = (const float*)d_in[12];
  const float* emb_W   = (const float*)d_in[13];
  const float* emb_b   = (const float*)d_in[14];
  const float* onorm_g = (const float*)d_in[15];
  const float* onorm_b = (const float*)d_in[16];
  const float* Wo      = (const float*)d_in[17];
  const float* bo      = (const float*)d_in[18];
  float* out = (float*)d_out;

  char* ws = (char*)d_ws;
  unsigned short* Ab = (unsigned short*)ws;                       // [32768][1024] bf16
  char* R = ws;                                                   // aliased after q-GEMM
  unsigned short* qb   = (unsigned short*)(ws + 67108864);        // [32768][1024] bf16
  unsigned short* Wq_t = (unsigned short*)(ws + 134217728);
  unsigned short* Wk_t = (unsigned short*)(ws + 136314880);
  unsigned short* Wv_t = (unsigned short*)(ws + 137887744);
  unsigned short* Wo_t = (unsigned short*)(ws + 139460608);
  float*          ssb  = (float*)(ws + 141557760);                // [32][2048]
  float*          sile = (float*)(ws + 141819904);                // [32][2048]
  float*          part = (float*)(ws + 142082048);                // [32][32][2048]
  // kv-phase aliases inside R (stream-serial after q-GEMM consumed Ab):
  unsigned short* xfb   = (unsigned short*)(R);                   // [2464][768] bf16
  float*          kbuf  = (float*)(R + 3784704);                  // [2464][1024] f32
  float*          vbuf  = (float*)(R + 13877248);                 // [2464][1024] f32
  unsigned short* attnT = (unsigned short*)(R + 23969792);        // [256][128][128] bf16

  const int Mq  = Bc * Tc;   // 32768
  const int Mkv = Bc * Nt;   // 2464

  // ---- q path ----
  ln_bf16_kernel<<<Mq, 256, 0, stream>>>(x, Ab, Dc, norm_g, norm_b);
  convT_bf16_kernel<<<dim3(Dc / 32, Dc / 32), 256, 0, stream>>>(Wq, Wq_t, Dc, Dc);
  convT_bf16_kernel<<<dim3(Dc / 32, Lc / 32), 256, 0, stream>>>(Wk, Wk_t, Lc, Dc);
  convT_bf16_kernel<<<dim3(Dc / 32, Lc / 32), 256, 0, stream>>>(Wv, Wv_t, Lc, Dc);
  convT_bf16_kernel<<<dim3(Dc / 32, Dc / 32), 256, 0, stream>>>(Wo, Wo_t, Dc, Dc);

  gemm_bf16_kernel<1, 0><<<(Dc / 128) * (Mq / 128), 256, 0, stream>>>(
      Ab, Wq_t, bq, qb, Mq, Dc, Dc, nullptr);
  softmax_q_bf16_kernel<<<(Mq * 8) / 4, 256, 0, stream>>>(qb);

  // ---- kv path (reuses region R) ----
  ln_bf16_kernel<<<Mkv, 256, 0, stream>>>(xf, xfb, Lc, tnorm_g, tnorm_b);
  gemm_bf16_kernel<0, 0><<<(Dc / 128) * 20, 256, 0, stream>>>(
      xfb, Wk_t, bk, kbuf, Mkv, Lc, Dc, nullptr);
  gemm_bf16_kernel<0, 0><<<(Dc / 128) * 20, 256, 0, stream>>>(
      xfb, Wv_t, bv_, vbuf, Mkv, Lc, Dc, nullptr);
  softmax_k_kernel<<<(Bc * Dc) / 256, 256, 0, stream>>>(kbuf);
  attn_einsum_kernel<<<Bc * 8, 256, 0, stream>>>(kbuf, vbuf, attnT);

  // ---- FiLM params: split-K ----
  silu_emb_kernel<<<(Bc * TEDc) / 1024, 256, 0, stream>>>(emb, sile);
  emb_part_kernel<<<dim3(8, 32), 256, 0, stream>>>(sile, emb_W, part);
  emb_reduce_kernel<<<(Bc * 2 * Dc) / 256, 256, 0, stream>>>(part, emb_b, ssb);

  // ---- y = q @ attn (MFMA, in place), LN+mod+SiLU, final GEMM + residual ----
  y_mfma_kernel<<<dim3(Tc / 128, Bc * 8), 256, 0, stream>>>(qb, attnT);
  ln_mod_silu_bf16_kernel<<<Mq, 256, 0, stream>>>(qb, ssb, onorm_g, onorm_b);
  gemm_bf16_kernel<0, 1><<<(Dc / 128) * (Mq / 128), 256, 0, stream>>>(
      qb, Wo_t, bo, out, Mq, Dc, Dc, x);
}